// Round 7
// baseline (143.890 us; speedup 1.0000x reference)
//
#include <hip/hip_runtime.h>
#include <cstddef>

#define NN 32
#define CC 96
#define TT 1024
#define PP 10240          // T*V, contiguous per (n,c)
#define NEG 0.1f
#define GCH 8             // k_gram: t-chunks per block (8 x 80p)

typedef __attribute__((ext_vector_type(8))) short s16x8;
typedef __attribute__((ext_vector_type(4))) float f32x4;
typedef unsigned short ushort_t;
typedef unsigned int uint_t;
typedef unsigned long long ull_t;

// ---- workspace layout (float offsets) ----
#define OFF_ATT  ((size_t)NN*128*300)              // attsum: f32 [N][300] (atomic accum)
#define OFF_WBF  (OFF_ATT + (size_t)NN*300)        // wbf: bf16 [288][96]
#define OFF_WFB  (OFF_WBF + (size_t)13824)         // wfb: bf16 [96][96] BN-folded
#define OFF_BF   (OFF_WFB + (size_t)4608)          // bfold: f32 [96]

#define VSTR 162   // vls pitch (ushorts): lh read spacing -> bank offsets {0,8,16,24}

__device__ __forceinline__ ushort_t f2bf(float f) {
    union { float f; uint_t u; } a; a.f = f;
    const uint_t r = a.u + 0x7FFFu + ((a.u >> 16) & 1u);   // RNE
    return (ushort_t)(r >> 16);
}
__device__ __forceinline__ float bf2f(ushort_t h) {
    union { uint_t u; float f; } a; a.u = ((uint_t)h) << 16;
    return a.f;
}
// inline tanh: no OCML call, no branches (allocator-friendly). |err| ~1e-7.
__device__ __forceinline__ float tanh_inl(float z) {
    z = fminf(fmaxf(z, -10.f), 10.f);
    const float e2 = __expf(2.f * z);
    return (e2 - 1.f) / (e2 + 1.f);
}

// ---------- prep: bf16 weights + BN fold + attsum zero ----------
__global__ void k_prep(const float* __restrict__ wqkv, const float* __restrict__ wff,
                       const float* __restrict__ bff,  const float* __restrict__ gam,
                       const float* __restrict__ bet,  const float* __restrict__ mu,
                       const float* __restrict__ var,  float* __restrict__ ws) {
    const int i = blockIdx.x * 256 + threadIdx.x;
    const int stride = gridDim.x * 256;
    ushort_t* wbf = (ushort_t*)(ws + OFF_WBF);
    for (int j = i; j < 288 * 96; j += stride) wbf[j] = f2bf(wqkv[j]);   // row-major [o][c]
    ushort_t* wfb = (ushort_t*)(ws + OFF_WFB);
    for (int j = i; j < 96 * 96; j += stride) {
        const int o = j / 96;                    // row-major [o][sc]
        const float A = gam[o] * rsqrtf(var[o] + 1e-5f);
        wfb[j] = f2bf(wff[j] * A);
    }
    for (int j = i; j < 96; j += stride) {
        const float A = gam[j] * rsqrtf(var[j] + 1e-5f);
        ws[OFF_BF + j] = (bff[j] - mu[j]) * A + bet[j];
    }
    for (int j = i; j < NN * 300; j += stride) ws[OFF_ATT + j] = 0.f;   // atomic accum
}

// ---------- gram: pipelined chunk loop; q,k proj + gram partials -> 1 atomic ----------
// UNCHANGED (HW-verified ~34 us).
__global__ __launch_bounds__(640) void k_gram(const float* __restrict__ x,
                                              const ushort_t* __restrict__ wbf,
                                              const float* __restrict__ bqkv,
                                              float* __restrict__ attsum) {
    __shared__ ushort_t xT[80][104];        // 16,640 B  xT[p][c]
    __shared__ ushort_t qk[6][8][10][36];   // 34,560 B  [role*3+s][t][u][cp(pad36)]
    __shared__ float red[6][100];           //  2,400 B  -> 53,600 total
    const int n = blockIdx.y, tcb = blockIdx.x;    // tcb in [0,16)
    const int tid = threadIdx.x;
    const int l = tid & 63, w = tid >> 6;          // w in [0,10)
    const int lr = l & 15, lh = l >> 4;
    const int ct = w >> 1, rth = w & 1;
    const int p2p = ct * 16 + lr;                  // P2 column owned by this lane

    int c4a[3], ppa[3];
#pragma unroll
    for (int it = 0; it < 3; it++) {
        const int i = tid + it * 640;              // i < 1920
        c4a[it] = i / 80; ppa[it] = i % 80;
    }

    const float* xn = x + (size_t)n * CC * PP;
    float xr[12];
    {
        const float* xsrc = xn + (size_t)(tcb * GCH) * 80;
#pragma unroll
        for (int it = 0; it < 3; it++)
#pragma unroll
            for (int r = 0; r < 4; r++)
                xr[it * 4 + r] = xsrc[(size_t)(4 * c4a[it] + r) * PP + ppa[it]];
    }

    float gacc = 0.f;
    for (int j = 0; j < GCH; j++) {
        // ---- pack xr -> xT (bf16, 4-c packed b64 writes) ----
#pragma unroll
        for (int it = 0; it < 3; it++) {
            const uint_t lo = (uint_t)f2bf(xr[it * 4 + 0]) | ((uint_t)f2bf(xr[it * 4 + 1]) << 16);
            const uint_t hi = (uint_t)f2bf(xr[it * 4 + 2]) | ((uint_t)f2bf(xr[it * 4 + 3]) << 16);
            *(ull_t*)&xT[ppa[it]][4 * c4a[it]] = (ull_t)lo | ((ull_t)hi << 32);
        }
        __syncthreads();

        // ---- prefetch next chunk into regs; drains under P2+P3 compute ----
        if (j + 1 < GCH) {
            const float* xsrc = xn + (size_t)(tcb * GCH + j + 1) * 80;
#pragma unroll
            for (int it = 0; it < 3; it++)
#pragma unroll
                for (int r = 0; r < 4; r++)
                    xr[it * 4 + r] = xsrc[(size_t)(4 * c4a[it] + r) * PP + ppa[it]];
        }

        // ---- P2: q,k projection; 10 wave-tasks = 5 ct x 2 roles, 6 rt each ----
        {
            s16x8 bfr[3];
#pragma unroll
            for (int kb = 0; kb < 3; kb++)
                bfr[kb] = *(const s16x8*)&xT[p2p][kb * 32 + lh * 8];
            ushort_t* qkf = (ushort_t*)qk;
#pragma unroll
            for (int jj = 0; jj < 6; jj++) {
                const int rt = rth * 6 + jj;
                f32x4 acc = {0.f, 0.f, 0.f, 0.f};
#pragma unroll
                for (int kb = 0; kb < 3; kb++) {
                    const s16x8 afr = *(const s16x8*)&wbf[(size_t)(rt * 16 + lr) * 96 + kb * 32 + lh * 8];
                    acc = __builtin_amdgcn_mfma_f32_16x16x32_bf16(afr, bfr[kb], acc, 0, 0, 0);
                }
                const int obase = rt * 16 + lh * 4;
                const float4 bb = *(const float4*)&bqkv[obase];
                const int role = rth;                 // rt<6 -> q, rt>=6 -> k
                const int orem = obase - role * 96;
                const int s = orem >> 5, cp0 = orem & 31;
                const uint_t lo = (uint_t)f2bf(acc[0] + bb.x) | ((uint_t)f2bf(acc[1] + bb.y) << 16);
                const uint_t hi = (uint_t)f2bf(acc[2] + bb.z) | ((uint_t)f2bf(acc[3] + bb.w) << 16);
                *(ull_t*)(qkf + ((size_t)(role * 3 + s) * 80 + p2p) * 36 + cp0) =
                    (ull_t)lo | ((ull_t)hi << 32);    // 8B-aligned (72B rows)
            }
        }
        __syncthreads();

        // ---- P3: gram G_s[u][v] = sum_{cp,t} q[s,cp,t,u] k[s,cp,t,v] ----
        if (w < 6) {
            const int s = w >> 1, th = w & 1;
            const int uv = lr > 9 ? 9 : lr;     // clamp garbage rows/cols (discarded)
            f32x4 g = {0.f, 0.f, 0.f, 0.f};
#pragma unroll
            for (int t4 = 0; t4 < 4; t4++) {
                const int t = th * 4 + t4;
                const ushort_t* qp = &qk[s][t][uv][lh * 8];       // 8B-aligned
                const ushort_t* kp = &qk[3 + s][t][uv][lh * 8];
                union { ull_t u[2]; s16x8 v; } ua, ub;
                ua.u[0] = *(const ull_t*)qp;  ua.u[1] = *(const ull_t*)(qp + 4);
                ub.u[0] = *(const ull_t*)kp;  ub.u[1] = *(const ull_t*)(kp + 4);
                g = __builtin_amdgcn_mfma_f32_16x16x32_bf16(ua.v, ub.v, g, 0, 0, 0);
            }
#pragma unroll
            for (int r = 0; r < 4; r++) {
                const int u = lh * 4 + r;
                if (u < 10 && lr < 10) red[w][u * 10 + lr] = g[r];
            }
        }
        __syncthreads();

        if (tid < 300) {
            const int s2 = tid / 100, r0 = tid % 100;
            gacc += red[s2 * 2][r0] + red[s2 * 2 + 1][r0];
        }
        // no barrier here: next red write is 2 barriers away (pack-B + P2-B)
    }
    if (tid < 300) atomicAdd(&attsum[(size_t)n * 300 + tid], gacc);
}

// ---------- mix: ILP-forced version ----------
// Changes vs r6:
//  * P1 split: issue ALL 24 staging loads, sched_barrier(0), then pack.
//    Fence stops the compiler sinking loads to uses (the 36-VGPR schedule's
//    6-round-trip serialization); forces 1 memory round-trip.
//  * FF: residual xres[24] issued up-front + sched_barrier(0) (un-sinkable).
//  * P4 unpack: 2-op bit form (two<<16 / two&0xFFFF0000), bit-identical.
__global__ __launch_bounds__(640) void k_mix(const float* __restrict__ x,
                                             const ushort_t* __restrict__ wbf,
                                             const float* __restrict__ bqkv,
                                             const float* __restrict__ attsum,
                                             const float* __restrict__ batt,
                                             const ushort_t* __restrict__ wfb,
                                             const float* __restrict__ bf,
                                             float* __restrict__ out,
                                             float* __restrict__ out_att0) {
    __shared__ ushort_t xv[160 * 104];   // 33,280 B (vls needs 96*VSTR=15,552 ush)
    __shared__ float Als[304];
    const int n = blockIdx.y, tc = blockIdx.x;   // tc in [0,64): 160 p
    const int tid = threadIdx.x;
    const int l = tid & 63, w = tid >> 6;        // w in [0,10)
    const int lr = l & 15, lh = l >> 4;
    const int p = w * 16 + lr;                   // wave w = ct

    // fused attention finalize (redundant per block; tc==0 writes att0 output)
    if (tid < 300) {
        const float a0 = tanh_inl(attsum[(size_t)n * 300 + tid] * (1.0f / 32768.0f));
        if (tc == 0) out_att0[(size_t)n * 300 + tid] = a0;
        const int s = tid / 100, r = tid % 100, u = r / 10, v = r % 10;
        const int pu = (u / 2 + 4) % 5, pv = (v / 2 + 4) % 5;   // PART_BODY closed form
        Als[tid] = a0 + batt[((n * 3 + s) * 5 + pu) * 5 + pv];
    }

    // ---- P1a: issue ALL staging loads (24 in flight, one round trip) ----
    const float* xsrc = x + (size_t)n * CC * PP + (size_t)tc * 160;
    float xr[24];
#pragma unroll
    for (int it = 0; it < 6; it++) {
        const int i = tid + it * 640;            // i < 3840 exactly
        const int c4 = i / 160, pp = i % 160;
#pragma unroll
        for (int r = 0; r < 4; r++)
            xr[it * 4 + r] = xsrc[(size_t)(4 * c4 + r) * PP + pp];
    }
    __builtin_amdgcn_sched_barrier(0);   // loads may NOT sink past this point

    // ---- P1b: pack -> xv-as-xT[p][c] (pitch 104), b64 writes ----
#pragma unroll
    for (int it = 0; it < 6; it++) {
        const int i = tid + it * 640;
        const int c4 = i / 160, pp = i % 160;
        const uint_t lo = (uint_t)f2bf(xr[it * 4 + 0]) | ((uint_t)f2bf(xr[it * 4 + 1]) << 16);
        const uint_t hi = (uint_t)f2bf(xr[it * 4 + 2]) | ((uint_t)f2bf(xr[it * 4 + 3]) << 16);
        *(ull_t*)&xv[pp * 104 + 4 * c4] = (ull_t)lo | ((ull_t)hi << 32);
    }
    __syncthreads();

    // ---- P2: v projection into registers (wave w = ct, 16 p each) ----
    s16x8 bfr[3];
#pragma unroll
    for (int kb = 0; kb < 3; kb++)
        bfr[kb] = *(const s16x8*)&xv[p * 104 + kb * 32 + lh * 8];
    ull_t vreg[6];
#pragma unroll
    for (int rt = 0; rt < 6; rt++) {
        f32x4 acc = {0.f, 0.f, 0.f, 0.f};
#pragma unroll
        for (int kb = 0; kb < 3; kb++) {
            const s16x8 afr = *(const s16x8*)&wbf[(size_t)(192 + rt * 16 + lr) * 96 + kb * 32 + lh * 8];
            acc = __builtin_amdgcn_mfma_f32_16x16x32_bf16(afr, bfr[kb], acc, 0, 0, 0);
        }
        const int ob = 192 + rt * 16 + lh * 4;
        const float4 bb = *(const float4*)&bqkv[ob];
        const uint_t lo = (uint_t)f2bf(acc[0] + bb.x) | ((uint_t)f2bf(acc[1] + bb.y) << 16);
        const uint_t hi = (uint_t)f2bf(acc[2] + bb.z) | ((uint_t)f2bf(acc[3] + bb.w) << 16);
        vreg[rt] = (ull_t)lo | ((ull_t)hi << 32);
    }
    __syncthreads();   // all reads of xv-as-xT complete

    // ---- P3: scatter v into xv-as-vls[o][p] (pitch VSTR) ----
#pragma unroll
    for (int rt = 0; rt < 6; rt++) {
        const int o = rt * 16 + lh * 4;
        xv[(o + 0) * VSTR + p] = (ushort_t)(vreg[rt]);
        xv[(o + 1) * VSTR + p] = (ushort_t)(vreg[rt] >> 16);
        xv[(o + 2) * VSTR + p] = (ushort_t)(vreg[rt] >> 32);
        xv[(o + 3) * VSTR + p] = (ushort_t)(vreg[rt] >> 48);
    }
    __syncthreads();

    // ---- P4: y0 = att @ v (scalar fmaf, aqk per-kb), yfr build ----
    const int tl = p / 10, u = p % 10;
    s16x8 yfr[3];
#pragma unroll
    for (int kb = 0; kb < 3; kb++) {
        float aqk[10];
#pragma unroll
        for (int v = 0; v < 10; v++) aqk[v] = Als[kb * 100 + u * 10 + v];
#pragma unroll
        for (int e = 0; e < 8; e++) {
            const int sc = kb * 32 + lh * 8 + e;
            const ushort_t* vr = &xv[sc * VSTR + tl * 10];
            float y0 = 0.f;
#pragma unroll
            for (int h = 0; h < 5; h++) {
                const uint_t two = *(const uint_t*)(vr + 2 * h);  // 4B-aligned
                union { uint_t uu; float ff; } lo, hi;
                lo.uu = two << 16;              // == bf2f(two & 0xFFFF), bit-identical
                hi.uu = two & 0xFFFF0000u;      // == bf2f(two >> 16),  bit-identical
                y0 = fmaf(aqk[2 * h],     lo.ff, y0);
                y0 = fmaf(aqk[2 * h + 1], hi.ff, y0);
            }
            yfr[kb][e] = (short)f2bf(y0);
        }
    }

    // ---- FF: residual loads up-front (un-sinkable), then MFMA + epilogue ----
    const size_t pbase = (size_t)n * CC * PP + (size_t)tc * 160;
    float xres[24];
#pragma unroll
    for (int rt = 0; rt < 6; rt++)
#pragma unroll
        for (int r = 0; r < 4; r++)
            xres[rt * 4 + r] = x[pbase + (size_t)(rt * 16 + lh * 4 + r) * PP + p];
    __builtin_amdgcn_sched_barrier(0);   // keep all 24 in flight together

#pragma unroll
    for (int rt = 0; rt < 6; rt++) {
        f32x4 acc = {0.f, 0.f, 0.f, 0.f};
#pragma unroll
        for (int kb = 0; kb < 3; kb++) {
            const s16x8 faf = *(const s16x8*)&wfb[(size_t)(rt * 16 + lr) * 96 + kb * 32 + lh * 8];
            acc = __builtin_amdgcn_mfma_f32_16x16x32_bf16(faf, yfr[kb], acc, 0, 0, 0);
        }
        const int ob = rt * 16 + lh * 4;
        const float4 bb = *(const float4*)&bf[ob];
#pragma unroll
        for (int r = 0; r < 4; r++) {
            const size_t idx = pbase + (size_t)(ob + r) * PP + p;
            const float rr = xres[rt * 4 + r] + acc[r] + ((const float*)&bb)[r];
            out[idx] = rr > 0.f ? rr : NEG * rr;
        }
    }
}

extern "C" void kernel_launch(void* const* d_in, const int* in_sizes, int n_in,
                              void* d_out, int out_size, void* d_ws, size_t ws_size,
                              hipStream_t stream) {
    const float* x    = (const float*)d_in[0];
    const float* batt = (const float*)d_in[1];
    const float* wqkv = (const float*)d_in[2];
    const float* bqkv = (const float*)d_in[3];
    const float* wff  = (const float*)d_in[4];
    const float* bff  = (const float*)d_in[5];
    const float* gam  = (const float*)d_in[6];
    const float* bet  = (const float*)d_in[7];
    const float* mu   = (const float*)d_in[8];
    const float* var  = (const float*)d_in[9];

    float* ws  = (float*)d_ws;
    float* out = (float*)d_out;
    float* out_att0 = out + (size_t)NN * CC * PP;

    float*    attsum = ws + OFF_ATT;
    ushort_t* wbf    = (ushort_t*)(ws + OFF_WBF);
    ushort_t* wfb    = (ushort_t*)(ws + OFF_WFB);
    float*    bfold  = ws + OFF_BF;

    hipLaunchKernelGGL(k_prep, dim3(64), dim3(256), 0, stream,
                       wqkv, wff, bff, gam, bet, mu, var, ws);
    hipLaunchKernelGGL(k_gram, dim3(128 / GCH, 32), dim3(640), 0, stream,
                       x, wbf, bqkv, attsum);
    hipLaunchKernelGGL(k_mix, dim3(64, 32), dim3(640), 0, stream,
                       x, wbf, bqkv, attsum, batt, wfb, bfold, out, out_att0);
}

// Round 8
// 134.943 us; speedup vs baseline: 1.0663x; 1.0663x over previous
//
#include <hip/hip_runtime.h>
#include <cstddef>

#define NN 32
#define CC 96
#define TT 1024
#define PP 10240          // T*V, contiguous per (n,c)
#define NEG 0.1f
#define GCH 8             // k_gram: t-chunks per block (8 x 80p)
#define MCH 4             // k_mix:  80p-chunks per block

typedef __attribute__((ext_vector_type(8))) short s16x8;
typedef __attribute__((ext_vector_type(4))) float f32x4;
typedef unsigned short ushort_t;
typedef unsigned int uint_t;
typedef unsigned long long ull_t;

// ---- workspace layout (float offsets) ----
#define OFF_ATT  ((size_t)NN*128*300)              // attsum: f32 [N][300] (atomic accum)
#define OFF_WBF  (OFF_ATT + (size_t)NN*300)        // wbf: bf16 [288][96]
#define OFF_WFB  (OFF_WBF + (size_t)13824)         // wfb: bf16 [96][96] BN-folded
#define OFF_BF   (OFF_WFB + (size_t)4608)          // bfold: f32 [96]

#define VP 82      // vls pitch (ushorts) for 80-p tiles

__device__ __forceinline__ ushort_t f2bf(float f) {
    union { float f; uint_t u; } a; a.f = f;
    const uint_t r = a.u + 0x7FFFu + ((a.u >> 16) & 1u);   // RNE
    return (ushort_t)(r >> 16);
}
__device__ __forceinline__ float bf2f(ushort_t h) {
    union { uint_t u; float f; } a; a.u = ((uint_t)h) << 16;
    return a.f;
}
// inline tanh: no OCML call, no branches. |err| ~1e-7.
__device__ __forceinline__ float tanh_inl(float z) {
    z = fminf(fmaxf(z, -10.f), 10.f);
    const float e2 = __expf(2.f * z);
    return (e2 - 1.f) / (e2 + 1.f);
}

// ---------- prep: bf16 weights + BN fold + attsum zero ----------
__global__ void k_prep(const float* __restrict__ wqkv, const float* __restrict__ wff,
                       const float* __restrict__ bff,  const float* __restrict__ gam,
                       const float* __restrict__ bet,  const float* __restrict__ mu,
                       const float* __restrict__ var,  float* __restrict__ ws) {
    const int i = blockIdx.x * 256 + threadIdx.x;
    const int stride = gridDim.x * 256;
    ushort_t* wbf = (ushort_t*)(ws + OFF_WBF);
    for (int j = i; j < 288 * 96; j += stride) wbf[j] = f2bf(wqkv[j]);   // row-major [o][c]
    ushort_t* wfb = (ushort_t*)(ws + OFF_WFB);
    for (int j = i; j < 96 * 96; j += stride) {
        const int o = j / 96;                    // row-major [o][sc]
        const float A = gam[o] * rsqrtf(var[o] + 1e-5f);
        wfb[j] = f2bf(wff[j] * A);
    }
    for (int j = i; j < 96; j += stride) {
        const float A = gam[j] * rsqrtf(var[j] + 1e-5f);
        ws[OFF_BF + j] = (bff[j] - mu[j]) * A + bet[j];
    }
    for (int j = i; j < NN * 300; j += stride) ws[OFF_ATT + j] = 0.f;   // atomic accum
}

// ---------- gram: pipelined chunk loop; q,k proj + gram partials -> 1 atomic ----------
// UNCHANGED (HW-verified ~34 us).
__global__ __launch_bounds__(640) void k_gram(const float* __restrict__ x,
                                              const ushort_t* __restrict__ wbf,
                                              const float* __restrict__ bqkv,
                                              float* __restrict__ attsum) {
    __shared__ ushort_t xT[80][104];        // 16,640 B  xT[p][c]
    __shared__ ushort_t qk[6][8][10][36];   // 34,560 B  [role*3+s][t][u][cp(pad36)]
    __shared__ float red[6][100];           //  2,400 B  -> 53,600 total
    const int n = blockIdx.y, tcb = blockIdx.x;    // tcb in [0,16)
    const int tid = threadIdx.x;
    const int l = tid & 63, w = tid >> 6;          // w in [0,10)
    const int lr = l & 15, lh = l >> 4;
    const int ct = w >> 1, rth = w & 1;
    const int p2p = ct * 16 + lr;                  // P2 column owned by this lane

    int c4a[3], ppa[3];
#pragma unroll
    for (int it = 0; it < 3; it++) {
        const int i = tid + it * 640;              // i < 1920
        c4a[it] = i / 80; ppa[it] = i % 80;
    }

    const float* xn = x + (size_t)n * CC * PP;
    float xr[12];
    {
        const float* xsrc = xn + (size_t)(tcb * GCH) * 80;
#pragma unroll
        for (int it = 0; it < 3; it++)
#pragma unroll
            for (int r = 0; r < 4; r++)
                xr[it * 4 + r] = xsrc[(size_t)(4 * c4a[it] + r) * PP + ppa[it]];
    }

    float gacc = 0.f;
    for (int j = 0; j < GCH; j++) {
        // ---- pack xr -> xT (bf16, 4-c packed b64 writes) ----
#pragma unroll
        for (int it = 0; it < 3; it++) {
            const uint_t lo = (uint_t)f2bf(xr[it * 4 + 0]) | ((uint_t)f2bf(xr[it * 4 + 1]) << 16);
            const uint_t hi = (uint_t)f2bf(xr[it * 4 + 2]) | ((uint_t)f2bf(xr[it * 4 + 3]) << 16);
            *(ull_t*)&xT[ppa[it]][4 * c4a[it]] = (ull_t)lo | ((ull_t)hi << 32);
        }
        __syncthreads();

        // ---- prefetch next chunk into regs; drains under P2+P3 compute ----
        if (j + 1 < GCH) {
            const float* xsrc = xn + (size_t)(tcb * GCH + j + 1) * 80;
#pragma unroll
            for (int it = 0; it < 3; it++)
#pragma unroll
                for (int r = 0; r < 4; r++)
                    xr[it * 4 + r] = xsrc[(size_t)(4 * c4a[it] + r) * PP + ppa[it]];
        }

        // ---- P2: q,k projection; 10 wave-tasks = 5 ct x 2 roles, 6 rt each ----
        {
            s16x8 bfr[3];
#pragma unroll
            for (int kb = 0; kb < 3; kb++)
                bfr[kb] = *(const s16x8*)&xT[p2p][kb * 32 + lh * 8];
            ushort_t* qkf = (ushort_t*)qk;
#pragma unroll
            for (int jj = 0; jj < 6; jj++) {
                const int rt = rth * 6 + jj;
                f32x4 acc = {0.f, 0.f, 0.f, 0.f};
#pragma unroll
                for (int kb = 0; kb < 3; kb++) {
                    const s16x8 afr = *(const s16x8*)&wbf[(size_t)(rt * 16 + lr) * 96 + kb * 32 + lh * 8];
                    acc = __builtin_amdgcn_mfma_f32_16x16x32_bf16(afr, bfr[kb], acc, 0, 0, 0);
                }
                const int obase = rt * 16 + lh * 4;
                const float4 bb = *(const float4*)&bqkv[obase];
                const int role = rth;                 // rt<6 -> q, rt>=6 -> k
                const int orem = obase - role * 96;
                const int s = orem >> 5, cp0 = orem & 31;
                const uint_t lo = (uint_t)f2bf(acc[0] + bb.x) | ((uint_t)f2bf(acc[1] + bb.y) << 16);
                const uint_t hi = (uint_t)f2bf(acc[2] + bb.z) | ((uint_t)f2bf(acc[3] + bb.w) << 16);
                *(ull_t*)(qkf + ((size_t)(role * 3 + s) * 80 + p2p) * 36 + cp0) =
                    (ull_t)lo | ((ull_t)hi << 32);    // 8B-aligned (72B rows)
            }
        }
        __syncthreads();

        // ---- P3: gram G_s[u][v] = sum_{cp,t} q[s,cp,t,u] k[s,cp,t,v] ----
        if (w < 6) {
            const int s = w >> 1, th = w & 1;
            const int uv = lr > 9 ? 9 : lr;     // clamp garbage rows/cols (discarded)
            f32x4 g = {0.f, 0.f, 0.f, 0.f};
#pragma unroll
            for (int t4 = 0; t4 < 4; t4++) {
                const int t = th * 4 + t4;
                const ushort_t* qp = &qk[s][t][uv][lh * 8];       // 8B-aligned
                const ushort_t* kp = &qk[3 + s][t][uv][lh * 8];
                union { ull_t u[2]; s16x8 v; } ua, ub;
                ua.u[0] = *(const ull_t*)qp;  ua.u[1] = *(const ull_t*)(qp + 4);
                ub.u[0] = *(const ull_t*)kp;  ub.u[1] = *(const ull_t*)(kp + 4);
                g = __builtin_amdgcn_mfma_f32_16x16x32_bf16(ua.v, ub.v, g, 0, 0, 0);
            }
#pragma unroll
            for (int r = 0; r < 4; r++) {
                const int u = lh * 4 + r;
                if (u < 10 && lr < 10) red[w][u * 10 + lr] = g[r];
            }
        }
        __syncthreads();

        if (tid < 300) {
            const int s2 = tid / 100, r0 = tid % 100;
            gacc += red[s2 * 2][r0] + red[s2 * 2 + 1][r0];
        }
        // no barrier here: next red write is 2 barriers away (pack-B + P2-B)
    }
    if (tid < 300) atomicAdd(&attsum[(size_t)n * 300 + tid], gacc);
}

// ---------- mix: k_gram-geometry chunk pipeline (80p, xr[12]) ----------
// 640 thr = 10 waves, per (n, 4-chunk group of 80p). Wave task (ct=w>>1, rth=w&1):
// P2 v-proj 3 rt each -> vls[o][p]. P4a: thread (g8=tid/80, pcol=tid%80) computes
// 12 y0 values (sc = m*8+g8: s = m>>2 is compile-time) -> y0T[p][sc] in the dead
// xT region. FF: yfr = 3x ds_read_b128 from y0T (no repack), 3 rt per wave.
__global__ __launch_bounds__(640) void k_mix(const float* __restrict__ x,
                                             const ushort_t* __restrict__ wbf,
                                             const float* __restrict__ bqkv,
                                             const float* __restrict__ attsum,
                                             const float* __restrict__ batt,
                                             const ushort_t* __restrict__ wfb,
                                             const float* __restrict__ bf,
                                             float* __restrict__ out,
                                             float* __restrict__ out_att0) {
    __shared__ ushort_t xT[80 * 104];    // 16,640 B; phase A: xT[p][c], phase B: y0T[p][sc]
    __shared__ ushort_t vls[96 * VP];    // 15,744 B  vls[o][p]
    __shared__ float Als[304];           // -> 33,600 B total
    const int n = blockIdx.y, tcb = blockIdx.x;   // tcb in [0,32)
    const int tid = threadIdx.x;
    const int l = tid & 63, w = tid >> 6;         // w in [0,10)
    const int lr = l & 15, lh = l >> 4;
    const int ct = w >> 1, rth = w & 1;
    const int plocal = ct * 16 + lr;              // P2/FF column owned by this lane

    // fused attention finalize (once per block; tcb==0 writes att0 output)
    if (tid < 300) {
        const float a0 = tanh_inl(attsum[(size_t)n * 300 + tid] * (1.0f / 32768.0f));
        if (tcb == 0) out_att0[(size_t)n * 300 + tid] = a0;
        const int s = tid / 100, r = tid % 100, u = r / 10, v = r % 10;
        const int pu = (u / 2 + 4) % 5, pv = (v / 2 + 4) % 5;   // PART_BODY closed form
        Als[tid] = a0 + batt[((n * 3 + s) * 5 + pu) * 5 + pv];
    }

    // staging mapping (3 iters x 4 channels), identical to k_gram
    int c4a[3], ppa[3];
#pragma unroll
    for (int it = 0; it < 3; it++) {
        const int i = tid + it * 640;             // i < 1920
        c4a[it] = i / 80; ppa[it] = i % 80;
    }
    // P4a mapping
    const int g8 = tid / 80;                      // group 0..7
    const int pcol = tid - g8 * 80;               // 0..79
    const int ucol = pcol % 10;
    const int tlb = pcol - ucol;                  // tl*10

    const float* xn = x + (size_t)n * CC * PP;
    float xr[12];
    {   // prologue: load chunk 0
        const float* xsrc = xn + (size_t)(tcb * MCH) * 80;
#pragma unroll
        for (int it = 0; it < 3; it++)
#pragma unroll
            for (int r = 0; r < 4; r++)
                xr[it * 4 + r] = xsrc[(size_t)(4 * c4a[it] + r) * PP + ppa[it]];
    }

    for (int j = 0; j < MCH; j++) {
        const int tc80 = tcb * MCH + j;
        // ---- pack xr -> xT[p][c] (b64 writes) ----
#pragma unroll
        for (int it = 0; it < 3; it++) {
            const uint_t lo = (uint_t)f2bf(xr[it * 4 + 0]) | ((uint_t)f2bf(xr[it * 4 + 1]) << 16);
            const uint_t hi = (uint_t)f2bf(xr[it * 4 + 2]) | ((uint_t)f2bf(xr[it * 4 + 3]) << 16);
            *(ull_t*)&xT[ppa[it] * 104 + 4 * c4a[it]] = (ull_t)lo | ((ull_t)hi << 32);
        }
        __syncthreads();

        // ---- prefetch next chunk into regs; drains under P2/P4a/FF compute ----
        if (j + 1 < MCH) {
            const float* xsrc = xn + (size_t)(tc80 + 1) * 80;
#pragma unroll
            for (int it = 0; it < 3; it++)
#pragma unroll
                for (int r = 0; r < 4; r++)
                    xr[it * 4 + r] = xsrc[(size_t)(4 * c4a[it] + r) * PP + ppa[it]];
        }

        // ---- P2: v projection, 3 rt per wave, immediate scatter to vls ----
        {
            s16x8 bfr[3];
#pragma unroll
            for (int kb = 0; kb < 3; kb++)
                bfr[kb] = *(const s16x8*)&xT[plocal * 104 + kb * 32 + lh * 8];
#pragma unroll
            for (int jj = 0; jj < 3; jj++) {
                const int rt = rth * 3 + jj;
                f32x4 acc = {0.f, 0.f, 0.f, 0.f};
#pragma unroll
                for (int kb = 0; kb < 3; kb++) {
                    const s16x8 afr = *(const s16x8*)&wbf[(size_t)(192 + rt * 16 + lr) * 96 + kb * 32 + lh * 8];
                    acc = __builtin_amdgcn_mfma_f32_16x16x32_bf16(afr, bfr[kb], acc, 0, 0, 0);
                }
                const int ob = 192 + rt * 16 + lh * 4;
                const float4 bb = *(const float4*)&bqkv[ob];
                const int o = rt * 16 + lh * 4;
                vls[(o + 0) * VP + plocal] = f2bf(acc[0] + bb.x);
                vls[(o + 1) * VP + plocal] = f2bf(acc[1] + bb.y);
                vls[(o + 2) * VP + plocal] = f2bf(acc[2] + bb.z);
                vls[(o + 3) * VP + plocal] = f2bf(acc[3] + bb.w);
            }
        }
        __syncthreads();

        // ---- P4a: y0 = att @ v; 12 values per thread -> y0T[p][sc] (xT region) ----
        {
            float aqk[10];
#pragma unroll
            for (int m = 0; m < 12; m++) {
                if ((m & 3) == 0) {                  // s = m>>2 is a literal per unroll
                    const int s = m >> 2;
#pragma unroll
                    for (int v = 0; v < 10; v++) aqk[v] = Als[s * 100 + ucol * 10 + v];
                }
                const int sc = m * 8 + g8;
                const ushort_t* vr = &vls[sc * VP + tlb];
                float y0 = 0.f;
#pragma unroll
                for (int h = 0; h < 5; h++) {
                    const uint_t two = *(const uint_t*)(vr + 2 * h);  // 4B-aligned
                    union { uint_t uu; float ff; } lo, hi;
                    lo.uu = two << 16;
                    hi.uu = two & 0xFFFF0000u;
                    y0 = fmaf(aqk[2 * h],     lo.ff, y0);
                    y0 = fmaf(aqk[2 * h + 1], hi.ff, y0);
                }
                xT[pcol * 104 + sc] = f2bf(y0);      // y0T write
            }
        }
        __syncthreads();

        // ---- FF: yfr from y0T (3x b128, no repack), 3 rt per wave, epilogue ----
        {
            s16x8 yfr[3];
#pragma unroll
            for (int kb = 0; kb < 3; kb++)
                yfr[kb] = *(const s16x8*)&xT[plocal * 104 + kb * 32 + lh * 8];
            const size_t pbase = (size_t)n * CC * PP + (size_t)tc80 * 80;
#pragma unroll
            for (int jj = 0; jj < 3; jj++) {
                const int rt = rth * 3 + jj;
                const int ob = rt * 16 + lh * 4;
                float xr4[4];
#pragma unroll
                for (int r = 0; r < 4; r++)
                    xr4[r] = x[pbase + (size_t)(ob + r) * PP + plocal];
                f32x4 acc = {0.f, 0.f, 0.f, 0.f};
#pragma unroll
                for (int kb = 0; kb < 3; kb++) {
                    const s16x8 faf = *(const s16x8*)&wfb[(size_t)(rt * 16 + lr) * 96 + kb * 32 + lh * 8];
                    acc = __builtin_amdgcn_mfma_f32_16x16x32_bf16(faf, yfr[kb], acc, 0, 0, 0);
                }
                const float4 bb = *(const float4*)&bf[ob];
#pragma unroll
                for (int r = 0; r < 4; r++) {
                    const size_t idx = pbase + (size_t)(ob + r) * PP + plocal;
                    const float rr = xr4[r] + acc[r] + ((const float*)&bb)[r];
                    out[idx] = rr > 0.f ? rr : NEG * rr;
                }
            }
        }
        __syncthreads();   // protect xT (next pack) and vls (next P2 write)
    }
}

extern "C" void kernel_launch(void* const* d_in, const int* in_sizes, int n_in,
                              void* d_out, int out_size, void* d_ws, size_t ws_size,
                              hipStream_t stream) {
    const float* x    = (const float*)d_in[0];
    const float* batt = (const float*)d_in[1];
    const float* wqkv = (const float*)d_in[2];
    const float* bqkv = (const float*)d_in[3];
    const float* wff  = (const float*)d_in[4];
    const float* bff  = (const float*)d_in[5];
    const float* gam  = (const float*)d_in[6];
    const float* bet  = (const float*)d_in[7];
    const float* mu   = (const float*)d_in[8];
    const float* var  = (const float*)d_in[9];

    float* ws  = (float*)d_ws;
    float* out = (float*)d_out;
    float* out_att0 = out + (size_t)NN * CC * PP;

    float*    attsum = ws + OFF_ATT;
    ushort_t* wbf    = (ushort_t*)(ws + OFF_WBF);
    ushort_t* wfb    = (ushort_t*)(ws + OFF_WFB);
    float*    bfold  = ws + OFF_BF;

    hipLaunchKernelGGL(k_prep, dim3(64), dim3(256), 0, stream,
                       wqkv, wff, bff, gam, bet, mu, var, ws);
    hipLaunchKernelGGL(k_gram, dim3(128 / GCH, 32), dim3(640), 0, stream,
                       x, wbf, bqkv, attsum);
    hipLaunchKernelGGL(k_mix, dim3(128 / MCH, 32), dim3(640), 0, stream,
                       x, wbf, bqkv, attsum, batt, wfb, bfold, out, out_att0);
}